// Round 1
// 324.293 us; speedup vs baseline: 1.6594x; 1.6594x over previous
//
#include <hip/hip_runtime.h>

typedef __bf16 bf16;
typedef __attribute__((ext_vector_type(4))) __bf16 bf16x4;
typedef __attribute__((ext_vector_type(8))) __bf16 bf16x8;
typedef __attribute__((ext_vector_type(4))) float f32x4;

__device__ __forceinline__ void gload_lds16(const void* g, void* l) {
  __builtin_amdgcn_global_load_lds(
      (const __attribute__((address_space(1))) unsigned int*)(unsigned long long)g,
      (__attribute__((address_space(3))) unsigned int*)(unsigned long long)l,
      16, 0, 0);
}

// ---------------- cast fp32 -> bf16 (x4 vectorized) ----------------
__global__ void cast_f32_bf16(const float* __restrict__ in, bf16* __restrict__ out, int n4) {
  int i = blockIdx.x * blockDim.x + threadIdx.x;
  if (i >= n4) return;
  float4 v = reinterpret_cast<const float4*>(in)[i];
  bf16x4 o;
  o[0] = (bf16)v.x; o[1] = (bf16)v.y; o[2] = (bf16)v.z; o[3] = (bf16)v.w;
  reinterpret_cast<bf16x4*>(out)[i] = o;
}

// ------- transpose+cast: V (rows x cols, f32) -> VT (cols x rows, bf16), batched -------
__global__ void transpose_cast(const float* __restrict__ V, bf16* __restrict__ VT,
                               int rows, int cols) {
  __shared__ bf16 tile[64][65];
  const int b = blockIdx.z;
  const float* Vb = V + (long)b * rows * cols;
  bf16* VTb = VT + (long)b * rows * cols;
  const int d0 = blockIdx.x * 64;
  const int k0 = blockIdx.y * 64;
  const int t = threadIdx.x;
  const int r = t >> 4;
  const int c4 = (t & 15) * 4;
#pragma unroll
  for (int p = 0; p < 4; ++p) {
    float4 v = *reinterpret_cast<const float4*>(&Vb[(long)(k0 + p * 16 + r) * cols + d0 + c4]);
    tile[p * 16 + r][c4 + 0] = (bf16)v.x;
    tile[p * 16 + r][c4 + 1] = (bf16)v.y;
    tile[p * 16 + r][c4 + 2] = (bf16)v.z;
    tile[p * 16 + r][c4 + 3] = (bf16)v.w;
  }
  __syncthreads();
#pragma unroll
  for (int p = 0; p < 4; ++p) {
    const int dd = p * 16 + r;
    bf16x4 o;
    o[0] = tile[c4 + 0][dd];
    o[1] = tile[c4 + 1][dd];
    o[2] = tile[c4 + 2][dd];
    o[3] = tile[c4 + 3][dd];
    *reinterpret_cast<bf16x4*>(&VTb[(long)(d0 + dd) * rows + k0 + c4]) = o;
  }
}

// ---------------- in-place row softmax, row length 2048, bf16 ----------------
__global__ void softmax_rows(bf16* __restrict__ S) {
  const long row = blockIdx.x;
  bf16* p = S + row * 2048;
  const int t = threadIdx.x;
  const int wid = t >> 6;
  const int lane = t & 63;
  bf16x8 v = *reinterpret_cast<bf16x8*>(p + t * 8);
  float f[8];
  float m = -3.0e38f;
#pragma unroll
  for (int j = 0; j < 8; ++j) { f[j] = (float)v[j]; m = fmaxf(m, f[j]); }
#pragma unroll
  for (int off = 32; off >= 1; off >>= 1) m = fmaxf(m, __shfl_xor(m, off));
  __shared__ float redm[4], reds[4];
  if (lane == 0) redm[wid] = m;
  __syncthreads();
  m = fmaxf(fmaxf(redm[0], redm[1]), fmaxf(redm[2], redm[3]));
  float s = 0.f;
#pragma unroll
  for (int j = 0; j < 8; ++j) { f[j] = __expf(f[j] - m); s += f[j]; }
#pragma unroll
  for (int off = 32; off >= 1; off >>= 1) s += __shfl_xor(s, off);
  if (lane == 0) reds[wid] = s;
  __syncthreads();
  s = reds[0] + reds[1] + reds[2] + reds[3];
  const float inv = 1.0f / s;
  bf16x8 o;
#pragma unroll
  for (int j = 0; j < 8; ++j) o[j] = (bf16)(f[j] * inv);
  *reinterpret_cast<bf16x8*>(p + t * 8) = o;
}

// ---------------- B^T GEMM: C[m][n] = scl * sum_k A[m][k]*B[n][k] (+bias[n]) ----------------
// 128x128 tile, BK=32, 256 threads (4 waves, 2x2 of 64x64), mfma 16x16x32 bf16.
// LDS row-major [128][32] with per-row XOR chunk swizzle:
//   LDS slot (row, kc) holds global 16B-chunk (row, kc ^ ((row>>1)&3)).
//   - global_load_lds source: 4 lanes cover each row's contiguous 64B (coalesced);
//     dest stays linear (HW requirement).
//   - ds_read_b128 fragment reads: XOR spreads 16-lane groups over all 32 banks,
//     exactly 2 lanes/bank -> conflict-free.
// XCD-aware bijective block swizzle (all grids % 8 == 0): contiguous id chunk per XCD
// -> batched gemms map 1 batch per XCD L2.
// MODE 0: bf16 out + bias; MODE 1: bf16 out * (1/scale from device ptr); MODE 2: f32 out.
template <int MODE>
__global__ void gemm_bt(const bf16* __restrict__ A, const bf16* __restrict__ Bm,
                        const float* __restrict__ bias, void* __restrict__ Cvoid,
                        const int* __restrict__ scale_ptr,
                        int M, int N, int K, long sA, long sB, long sC) {
  __shared__ bf16 Alds[128][32];
  __shared__ bf16 Blds[128][32];
  const int t = threadIdx.x;
  const int lane = t & 63;
  const int wid = t >> 6;
  const int wm = wid >> 1;
  const int wn = wid & 1;

  // ---- XCD-aware bijective swizzle of the linear workgroup id ----
  const int gx = gridDim.x, gy = gridDim.y;
  const int nwg = gx * gy * gridDim.z;
  int id = blockIdx.x + gx * (blockIdx.y + gy * blockIdx.z);
  if ((nwg & 7) == 0) {
    const int cpx = nwg >> 3;
    id = (id & 7) * cpx + (id >> 3);
  }
  const int bx = id % gx;
  const int by = (id / gx) % gy;
  const int bz = id / (gx * gy);

  const bf16* Ab = A + (long)bz * sA;
  const bf16* Bb = Bm + (long)bz * sB;
  const int tile_m = by * 128;
  const int tile_n = bx * 128;

  // staging: 512 16B-chunks per operand; thread t covers chunk t and t+256.
  // chunk c: row=c>>2, kc=c&3; source pre-swizzled: global chunk (row, kc^((row>>1)&3)).
  const int r0 = t >> 2;
  const int kc0 = t & 3;
  const int sk = (kc0 ^ ((r0 >> 1) & 3)) * 8;  // swizzled elem offset within row
  const bf16* gA0 = Ab + (long)(tile_m + r0) * K + sk;
  const bf16* gA1 = gA0 + (long)64 * K;   // chunk t+256: row+64, same swizzle (64%8==0)
  const bf16* gB0 = Bb + (long)(tile_n + r0) * K + sk;
  const bf16* gB1 = gB0 + (long)64 * K;
  bf16* lA0 = &Alds[0][0] + wid * 512;    // wave-uniform LDS base (HW adds lane*16B)
  bf16* lA1 = lA0 + 2048;
  bf16* lB0 = &Blds[0][0] + wid * 512;
  bf16* lB1 = lB0 + 2048;

  // fragment reads: lane wants (row = w*64 + i*16 + frow, k-chunk fkc=lane>>4);
  // physical chunk = fkc ^ ((row>>1)&3); row%8 invariant across i/w offsets.
  const int frow = lane & 15;
  const int fkc = lane >> 4;
  const int pko = (fkc ^ ((frow >> 1) & 3)) * 8;
  const bf16* aFrag = &Alds[wm * 64 + frow][pko];
  const bf16* bFrag = &Blds[wn * 64 + frow][pko];

  f32x4 acc[4][4] = {};
  const int nk = K >> 5;
  for (int kt = 0; kt < nk; ++kt) {
    const int ko = kt * 32;
    gload_lds16(gA0 + ko, lA0);
    gload_lds16(gA1 + ko, lA1);
    gload_lds16(gB0 + ko, lB0);
    gload_lds16(gB1 + ko, lB1);
    __syncthreads();  // compiler drains vmcnt(0) before s_barrier -> staging visible
    bf16x8 af[4], bfv[4];
#pragma unroll
    for (int i = 0; i < 4; ++i) {
      af[i] = *reinterpret_cast<const bf16x8*>(aFrag + i * 512);   // +16 rows
      bfv[i] = *reinterpret_cast<const bf16x8*>(bFrag + i * 512);
    }
#pragma unroll
    for (int mi = 0; mi < 4; ++mi)
#pragma unroll
      for (int ni = 0; ni < 4; ++ni)
        acc[mi][ni] = __builtin_amdgcn_mfma_f32_16x16x32_bf16(af[mi], bfv[ni], acc[mi][ni], 0, 0, 0);
    __syncthreads();  // all waves done reading before next stage overwrites
  }

  float scl = 1.0f;
  if (MODE == 1) {
    const int iv = scale_ptr[0];
    const float fv = __int_as_float(iv);
    const float sv = (iv > 0 && iv < (1 << 20)) ? (float)iv : fv;  // int32 or float32 encoding
    scl = 1.0f / sv;
  }
  // C/D layout (verified m89/m91): col=lane&15, row=(lane>>4)*4+reg
  const int rb = tile_m + wm * 64 + ((lane >> 4) << 2);
  const int cb = tile_n + wn * 64 + (lane & 15);
  if (MODE == 2) {
    float* C = reinterpret_cast<float*>(Cvoid) + (long)bz * sC;
#pragma unroll
    for (int mi = 0; mi < 4; ++mi)
#pragma unroll
      for (int ni = 0; ni < 4; ++ni)
#pragma unroll
        for (int r = 0; r < 4; ++r)
          C[(long)(rb + mi * 16 + r) * N + (cb + ni * 16)] = acc[mi][ni][r];
  } else {
    bf16* C = reinterpret_cast<bf16*>(Cvoid) + (long)bz * sC;
#pragma unroll
    for (int ni = 0; ni < 4; ++ni) {
      const int col = cb + ni * 16;
      const float bv = (MODE == 0) ? bias[col] : 0.0f;
#pragma unroll
      for (int mi = 0; mi < 4; ++mi)
#pragma unroll
        for (int r = 0; r < 4; ++r)
          C[(long)(rb + mi * 16 + r) * N + col] = (bf16)(acc[mi][ni][r] * scl + bv);
    }
  }
}

extern "C" void kernel_launch(void* const* d_in, const int* in_sizes, int n_in,
                              void* d_out, int out_size, void* d_ws, size_t ws_size,
                              hipStream_t stream) {
  (void)in_sizes; (void)n_in; (void)out_size; (void)ws_size;
  const float* query = (const float*)d_in[0];
  const float* key   = (const float*)d_in[1];
  const float* value = (const float*)d_in[2];
  const float* Wq    = (const float*)d_in[3];
  const float* bq    = (const float*)d_in[4];
  const float* Wk    = (const float*)d_in[5];
  const float* bk    = (const float*)d_in[6];
  const int*   scale = (const int*)d_in[7];

  const int L = 2048, D = 1024;
  // ws layout (bytes):
  //   [0,   64M): q_cast(32M) + k_cast(32M), later reused as S/P (8*2048*2048 bf16 = 64M exactly)
  //   [64M, 96M): Qp   [96M,128M): Kp   [128M,160M): VT   [160M,162M): Wq_b  [162M,164M): Wk_b
  char* ws = (char*)d_ws;
  bf16* q_cast = (bf16*)ws;
  bf16* k_cast = q_cast + (long)16384 * 1024;
  bf16* S      = q_cast;
  bf16* Qp     = (bf16*)(ws + (size_t)67108864);
  bf16* Kp     = (bf16*)(ws + (size_t)100663296);
  bf16* VT     = (bf16*)(ws + (size_t)134217728);
  bf16* Wqb    = (bf16*)(ws + (size_t)167772160);
  bf16* Wkb    = (bf16*)(ws + (size_t)169869312);

  cast_f32_bf16<<<16384, 256, 0, stream>>>(query, q_cast, 4194304);
  cast_f32_bf16<<<16384, 256, 0, stream>>>(key,   k_cast, 4194304);
  cast_f32_bf16<<<1024,  256, 0, stream>>>(Wq, Wqb, 262144);
  cast_f32_bf16<<<1024,  256, 0, stream>>>(Wk, Wkb, 262144);
  transpose_cast<<<dim3(16, 32, 8), 256, 0, stream>>>(value, VT, 2048, 1024);

  // projections: Qp = q_cast @ Wq^T + bq   (M=16384, N=1024, K=1024)
  gemm_bt<0><<<dim3(8, 128, 1), 256, 0, stream>>>(q_cast, Wqb, bq, Qp, nullptr,
                                                  16384, 1024, 1024, 0, 0, 0);
  gemm_bt<0><<<dim3(8, 128, 1), 256, 0, stream>>>(k_cast, Wkb, bk, Kp, nullptr,
                                                  16384, 1024, 1024, 0, 0, 0);
  // scores: S[b] = (Qp[b] @ Kp[b]^T) / scale   (M=N=2048, K=1024, batched over 8)
  gemm_bt<1><<<dim3(16, 16, 8), 256, 0, stream>>>(Qp, Kp, nullptr, S, scale,
                                                  2048, 2048, 1024,
                                                  (long)L * D, (long)L * D, (long)L * L);
  softmax_rows<<<16384, 256, 0, stream>>>(S);
  // out: O[b] = P[b] @ VT[b]^T  (M=2048, N=1024, K=2048, f32 out)
  gemm_bt<2><<<dim3(8, 16, 8), 256, 0, stream>>>(S, VT, nullptr, d_out, nullptr,
                                                 2048, 1024, 2048,
                                                 (long)L * L, (long)D * L, (long)L * D);
}

// Round 2
// 289.025 us; speedup vs baseline: 1.8619x; 1.1220x over previous
//
#include <hip/hip_runtime.h>

typedef __bf16 bf16;
typedef __attribute__((ext_vector_type(4))) __bf16 bf16x4;
typedef __attribute__((ext_vector_type(8))) __bf16 bf16x8;
typedef __attribute__((ext_vector_type(4))) float f32x4;

__device__ __forceinline__ void gload_lds16(const void* g, void* l) {
  __builtin_amdgcn_global_load_lds(
      (const __attribute__((address_space(1))) unsigned int*)(unsigned long long)g,
      (__attribute__((address_space(3))) unsigned int*)(unsigned long long)l,
      16, 0, 0);
}

// ---------------- cast fp32 -> bf16 (x4 vectorized) ----------------
__global__ void cast_f32_bf16(const float* __restrict__ in, bf16* __restrict__ out, int n4) {
  int i = blockIdx.x * blockDim.x + threadIdx.x;
  if (i >= n4) return;
  float4 v = reinterpret_cast<const float4*>(in)[i];
  bf16x4 o;
  o[0] = (bf16)v.x; o[1] = (bf16)v.y; o[2] = (bf16)v.z; o[3] = (bf16)v.w;
  reinterpret_cast<bf16x4*>(out)[i] = o;
}

// ------- transpose+cast: V (rows x cols, f32) -> VT (cols x rows, bf16), batched -------
__global__ void transpose_cast(const float* __restrict__ V, bf16* __restrict__ VT,
                               int rows, int cols) {
  __shared__ bf16 tile[64][65];
  const int b = blockIdx.z;
  const float* Vb = V + (long)b * rows * cols;
  bf16* VTb = VT + (long)b * rows * cols;
  const int d0 = blockIdx.x * 64;
  const int k0 = blockIdx.y * 64;
  const int t = threadIdx.x;
  const int r = t >> 4;
  const int c4 = (t & 15) * 4;
#pragma unroll
  for (int p = 0; p < 4; ++p) {
    float4 v = *reinterpret_cast<const float4*>(&Vb[(long)(k0 + p * 16 + r) * cols + d0 + c4]);
    tile[p * 16 + r][c4 + 0] = (bf16)v.x;
    tile[p * 16 + r][c4 + 1] = (bf16)v.y;
    tile[p * 16 + r][c4 + 2] = (bf16)v.z;
    tile[p * 16 + r][c4 + 3] = (bf16)v.w;
  }
  __syncthreads();
#pragma unroll
  for (int p = 0; p < 4; ++p) {
    const int dd = p * 16 + r;
    bf16x4 o;
    o[0] = tile[c4 + 0][dd];
    o[1] = tile[c4 + 1][dd];
    o[2] = tile[c4 + 2][dd];
    o[3] = tile[c4 + 3][dd];
    *reinterpret_cast<bf16x4*>(&VTb[(long)(d0 + dd) * rows + k0 + c4]) = o;
  }
}

// ---------------- in-place row softmax, row length 2048, bf16 ----------------
__global__ void softmax_rows(bf16* __restrict__ S) {
  const long row = blockIdx.x;
  bf16* p = S + row * 2048;
  const int t = threadIdx.x;
  const int wid = t >> 6;
  const int lane = t & 63;
  bf16x8 v = *reinterpret_cast<bf16x8*>(p + t * 8);
  float f[8];
  float m = -3.0e38f;
#pragma unroll
  for (int j = 0; j < 8; ++j) { f[j] = (float)v[j]; m = fmaxf(m, f[j]); }
#pragma unroll
  for (int off = 32; off >= 1; off >>= 1) m = fmaxf(m, __shfl_xor(m, off));
  __shared__ float redm[4], reds[4];
  if (lane == 0) redm[wid] = m;
  __syncthreads();
  m = fmaxf(fmaxf(redm[0], redm[1]), fmaxf(redm[2], redm[3]));
  float s = 0.f;
#pragma unroll
  for (int j = 0; j < 8; ++j) { f[j] = __expf(f[j] - m); s += f[j]; }
#pragma unroll
  for (int off = 32; off >= 1; off >>= 1) s += __shfl_xor(s, off);
  if (lane == 0) reds[wid] = s;
  __syncthreads();
  s = reds[0] + reds[1] + reds[2] + reds[3];
  const float inv = 1.0f / s;
  bf16x8 o;
#pragma unroll
  for (int j = 0; j < 8; ++j) o[j] = (bf16)(f[j] * inv);
  *reinterpret_cast<bf16x8*>(p + t * 8) = o;
}

// ---------------- B^T GEMM, 256x256 tile, BK=64, 8-phase schedule ----------------
// 512 threads = 8 waves (2 M x 4 N), each wave owns a 128x64 output sub-tile
// (8 m-frags x 4 n-frags of 16x16, mfma_f32_16x16x32_bf16, acc[8][4] f32x4).
// LDS [buf2][op2][half2][128][64] bf16 = 128 KiB, double-buffered.
// XOR chunk swizzle within each 128B row (chunk ^= row&7): conflict-free
// ds_read_b128 (2 lanes/bank) with linear global_load_lds dest (source pre-swizzled).
// Per K-tile: 4 phases {ds_read quadrant | issue prefetch -> s_barrier ->
// lgkmcnt(0) -> setprio(1) 16xMFMA setprio(0) -> s_barrier}; prefetch of kt+1
// issued in phases 0-1, drained by counted wait only at the tile boundary
// (~2-3 phases of MFMA cover the load latency). No __syncthreads in the loop.
// MODE 0: bf16 out + bias; MODE 1: bf16 out * (1/scale); MODE 2: f32 out.

#define BARRIER __builtin_amdgcn_s_barrier()
#define LGKM0                                              \
  do {                                                     \
    asm volatile("s_waitcnt lgkmcnt(0)" ::: "memory");     \
    __builtin_amdgcn_sched_barrier(0);                     \
  } while (0)
#define VM0                                                \
  do {                                                     \
    asm volatile("s_waitcnt vmcnt(0)" ::: "memory");       \
    __builtin_amdgcn_sched_barrier(0);                     \
  } while (0)

#define STAGE_A(buf, ko)                                        \
  {                                                             \
    bf16* l_ = ldsd + (buf) * 32768;                            \
    const bf16* g_ = gA + (ko);                                 \
    gload_lds16(g_, l_);                                        \
    gload_lds16(g_ + rK64, l_ + 4096);                          \
    gload_lds16(g_ + rK128, l_ + 8192);                         \
    gload_lds16(g_ + rK128 + rK64, l_ + 12288);                 \
  }
#define STAGE_B(buf, ko)                                        \
  {                                                             \
    bf16* l_ = ldsd + (buf) * 32768 + 16384;                    \
    const bf16* g_ = gB + (ko);                                 \
    gload_lds16(g_, l_);                                        \
    gload_lds16(g_ + rK64, l_ + 4096);                          \
    gload_lds16(g_ + rK128, l_ + 8192);                         \
    gload_lds16(g_ + rK128 + rK64, l_ + 12288);                 \
  }

#define LOADA(buf, mq)                                                        \
  {                                                                           \
    const bf16* p_ = aBase + (buf) * 32768 + (mq) * 4096;                     \
    _Pragma("unroll") for (int m_ = 0; m_ < 4; ++m_) {                        \
      a[m_][0] = *reinterpret_cast<const bf16x8*>(p_ + m_ * 1024 + pk0);      \
      a[m_][1] = *reinterpret_cast<const bf16x8*>(p_ + m_ * 1024 + pk1);      \
    }                                                                         \
  }
#define LOADB(buf, nq)                                                        \
  {                                                                           \
    const bf16* p_ = bBase + (buf) * 32768 + (nq) * 2048;                     \
    _Pragma("unroll") for (int n_ = 0; n_ < 2; ++n_) {                        \
      b[(nq) * 2 + n_][0] = *reinterpret_cast<const bf16x8*>(p_ + n_ * 1024 + pk0); \
      b[(nq) * 2 + n_][1] = *reinterpret_cast<const bf16x8*>(p_ + n_ * 1024 + pk1); \
    }                                                                         \
  }

#define MFMAQ(mq, nq)                                                         \
  _Pragma("unroll") for (int m_ = 0; m_ < 4; ++m_)                            \
  _Pragma("unroll") for (int n_ = 0; n_ < 2; ++n_)                            \
  _Pragma("unroll") for (int ks_ = 0; ks_ < 2; ++ks_)                         \
      acc[(mq) * 4 + m_][(nq) * 2 + n_] =                                     \
          __builtin_amdgcn_mfma_f32_16x16x32_bf16(                            \
              a[m_][ks_], b[(nq) * 2 + n_][ks_],                              \
              acc[(mq) * 4 + m_][(nq) * 2 + n_], 0, 0, 0);

template <int MODE>
__global__ __launch_bounds__(512, 2)
void gemm_bt(const bf16* __restrict__ A, const bf16* __restrict__ Bm,
             const float* __restrict__ bias, void* __restrict__ Cvoid,
             const int* __restrict__ scale_ptr,
             int M, int N, int K, long sA, long sB, long sC) {
  __shared__ bf16 lds[2][2][2][128][64];  // [buf][opA/B][half][row][64k] = 128 KiB
  const int t = threadIdx.x;
  const int lane = t & 63;
  const int wid = t >> 6;   // 0..7
  const int wm = wid >> 2;  // 0..1
  const int wn = wid & 3;   // 0..3
  (void)M;

  // XCD-aware bijective swizzle (all grids here have nwg % 8 == 0)
  const int gx = gridDim.x, gy = gridDim.y;
  const int nwg = gx * gy * gridDim.z;
  int id = blockIdx.x + gx * (blockIdx.y + gy * blockIdx.z);
  {
    const int cpx = nwg >> 3;
    id = (id & 7) * cpx + (id >> 3);
  }
  const int bx = id % gx;
  const int by = (id / gx) % gy;
  const int bz = id / (gx * gy);

  const bf16* Ab = A + (long)bz * sA;
  const bf16* Bb = Bm + (long)bz * sB;
  const int tile_m = by * 256;
  const int tile_n = bx * 256;

  // staging: half-tile = [128][64] = 1024 x 16B chunks; thread t covers chunk t
  // (row=t>>3, kc=t&7) and chunk t+512 (row+64). Source pre-swizzled: global
  // chunk = kc ^ (row&7). Dest linear: elem = chunk*8 (wave-uniform + lane*16B).
  const int srow = t >> 3;
  const int skc = t & 7;
  const int soff = ((skc ^ (srow & 7)) << 3);
  const bf16* gA = Ab + (long)(tile_m + srow) * K + soff;
  const bf16* gB = Bb + (long)(tile_n + srow) * K + soff;
  const long rK64 = (long)K << 6;    // +64 rows
  const long rK128 = (long)K << 7;   // +128 rows (half stride)
  bf16* const ldsd = &lds[0][0][0][0][0] + wid * 512;

  // fragment reads: lane reads row frow=lane&15 of its half, logical k-chunk
  // ks*4+(lane>>4); physical chunk = logical ^ (row&7) = logical ^ (lane&7).
  const int frow = lane & 15;
  const int pk0 = (((lane >> 4) ^ (lane & 7))) << 3;
  const int pk1 = (((4 | (lane >> 4)) ^ (lane & 7))) << 3;
  const bf16* aBase = &lds[0][0][wm][frow][0];
  const bf16* bBase = &lds[0][1][wn >> 1][(wn & 1) * 64 + frow][0];

  bf16x8 a[4][2], b[4][2];
  f32x4 acc[8][4] = {};

  // prologue: stage tile 0 fully, drain once, sync
  STAGE_A(0, 0)
  STAGE_B(0, 0)
  VM0;
  BARRIER;

  const int NK = K >> 6;
  int c = 0;
  for (int kt = 0; kt < NK - 1; ++kt, c ^= 1) {
    const long ko = (long)(kt + 1) << 6;
    // P0: quadrant (0,0); prefetch A of kt+1
    LOADA(c, 0)
    LOADB(c, 0)
    STAGE_A(c ^ 1, ko)
    BARRIER;
    LGKM0;
    __builtin_amdgcn_s_setprio(1);
    MFMAQ(0, 0)
    __builtin_amdgcn_s_setprio(0);
    BARRIER;
    // P1: quadrant (0,1); prefetch B of kt+1
    LOADB(c, 1)
    STAGE_B(c ^ 1, ko)
    BARRIER;
    LGKM0;
    __builtin_amdgcn_s_setprio(1);
    MFMAQ(0, 1)
    __builtin_amdgcn_s_setprio(0);
    BARRIER;
    // P2: quadrant (1,0)
    LOADA(c, 1)
    BARRIER;
    LGKM0;
    __builtin_amdgcn_s_setprio(1);
    MFMAQ(1, 0)
    __builtin_amdgcn_s_setprio(0);
    BARRIER;
    // P3: boundary — drain kt+1's loads (issued 2-3 phases ago), sync, last quadrant
    VM0;
    BARRIER;
    __builtin_amdgcn_s_setprio(1);
    MFMAQ(1, 1)
    __builtin_amdgcn_s_setprio(0);
  }
  // peeled last tile: pure compute from buf c (no staging, compiler-managed waits)
  LOADA(c, 0)
  LOADB(c, 0)
  LOADB(c, 1)
  MFMAQ(0, 0)
  MFMAQ(0, 1)
  LOADA(c, 1)
  MFMAQ(1, 0)
  MFMAQ(1, 1)

  float scl = 1.0f;
  if (MODE == 1) {
    const int iv = scale_ptr[0];
    const float fv = __int_as_float(iv);
    const float sv = (iv > 0 && iv < (1 << 20)) ? (float)iv : fv;
    scl = 1.0f / sv;
  }
  // C/D layout (verified m89/m91): col=lane&15, row=(lane>>4)*4+reg
  const int rb = tile_m + wm * 128 + ((lane >> 4) << 2);
  const int cb = tile_n + wn * 64 + (lane & 15);
  if (MODE == 2) {
    float* C = reinterpret_cast<float*>(Cvoid) + (long)bz * sC;
#pragma unroll
    for (int mf = 0; mf < 8; ++mf)
#pragma unroll
      for (int nf = 0; nf < 4; ++nf)
#pragma unroll
        for (int r = 0; r < 4; ++r)
          C[(long)(rb + mf * 16 + r) * N + (cb + nf * 16)] = acc[mf][nf][r];
  } else {
    bf16* C = reinterpret_cast<bf16*>(Cvoid) + (long)bz * sC;
#pragma unroll
    for (int nf = 0; nf < 4; ++nf) {
      const int col = cb + nf * 16;
      const float bv = (MODE == 0) ? bias[col] : 0.0f;
#pragma unroll
      for (int mf = 0; mf < 8; ++mf)
#pragma unroll
        for (int r = 0; r < 4; ++r)
          C[(long)(rb + mf * 16 + r) * N + col] = (bf16)(acc[mf][nf][r] * scl + bv);
    }
  }
}

extern "C" void kernel_launch(void* const* d_in, const int* in_sizes, int n_in,
                              void* d_out, int out_size, void* d_ws, size_t ws_size,
                              hipStream_t stream) {
  (void)in_sizes; (void)n_in; (void)out_size; (void)ws_size;
  const float* query = (const float*)d_in[0];
  const float* key   = (const float*)d_in[1];
  const float* value = (const float*)d_in[2];
  const float* Wq    = (const float*)d_in[3];
  const float* bq    = (const float*)d_in[4];
  const float* Wk    = (const float*)d_in[5];
  const float* bk    = (const float*)d_in[6];
  const int*   scale = (const int*)d_in[7];

  const int L = 2048, D = 1024;
  // ws layout (bytes):
  //   [0,   64M): q_cast(32M) + k_cast(32M), later reused as S/P (8*2048*2048 bf16 = 64M exactly)
  //   [64M, 96M): Qp   [96M,128M): Kp   [128M,160M): VT   [160M,162M): Wq_b  [162M,164M): Wk_b
  char* ws = (char*)d_ws;
  bf16* q_cast = (bf16*)ws;
  bf16* k_cast = q_cast + (long)16384 * 1024;
  bf16* S      = q_cast;
  bf16* Qp     = (bf16*)(ws + (size_t)67108864);
  bf16* Kp     = (bf16*)(ws + (size_t)100663296);
  bf16* VT     = (bf16*)(ws + (size_t)134217728);
  bf16* Wqb    = (bf16*)(ws + (size_t)167772160);
  bf16* Wkb    = (bf16*)(ws + (size_t)169869312);

  cast_f32_bf16<<<16384, 256, 0, stream>>>(query, q_cast, 4194304);
  cast_f32_bf16<<<16384, 256, 0, stream>>>(key,   k_cast, 4194304);
  cast_f32_bf16<<<1024,  256, 0, stream>>>(Wq, Wqb, 262144);
  cast_f32_bf16<<<1024,  256, 0, stream>>>(Wk, Wkb, 262144);
  transpose_cast<<<dim3(16, 32, 8), 256, 0, stream>>>(value, VT, 2048, 1024);

  // projections: Qp = q_cast @ Wq^T + bq   (M=16384, N=1024, K=1024)
  gemm_bt<0><<<dim3(4, 64, 1), 512, 0, stream>>>(q_cast, Wqb, bq, Qp, nullptr,
                                                 16384, 1024, 1024, 0, 0, 0);
  gemm_bt<0><<<dim3(4, 64, 1), 512, 0, stream>>>(k_cast, Wkb, bk, Kp, nullptr,
                                                 16384, 1024, 1024, 0, 0, 0);
  // scores: S[b] = (Qp[b] @ Kp[b]^T) / scale   (M=N=2048, K=1024, batched over 8)
  gemm_bt<1><<<dim3(8, 8, 8), 512, 0, stream>>>(Qp, Kp, nullptr, S, scale,
                                                2048, 2048, 1024,
                                                (long)L * D, (long)L * D, (long)L * L);
  softmax_rows<<<16384, 256, 0, stream>>>(S);
  // out: O[b] = P[b] @ VT[b]^T  (M=2048, N=1024, K=2048, f32 out)
  gemm_bt<2><<<dim3(4, 8, 8), 512, 0, stream>>>(S, VT, nullptr, d_out, nullptr,
                                                2048, 1024, 2048,
                                                (long)L * L, (long)D * L, (long)L * D);
}